// Round 4
// baseline (151.848 us; speedup 1.0000x reference)
//
#include <hip/hip_runtime.h>
#include <hip/hip_bf16.h>

#define N_ROWS 8192
#define DIM    128
#define TWO_N  16384
#define NBLK   64                         // 256-row/col block stripes
#define NTRI   (NBLK * (NBLK + 1) / 2)    // 2080 triangular blocks
#define EXP_TWO 7.38905609893065f
// sqrt(2 * log2(e)): folding exp(2*dot) == exp2(SCALE^2 * dot) into the operands
#define H_SCALE 1.6986436f

typedef __attribute__((ext_vector_type(8))) short short8;
typedef __attribute__((ext_vector_type(4))) float float4v;

__device__ inline float fast_exp2(float x) {
#if __has_builtin(__builtin_amdgcn_exp2f)
  return __builtin_amdgcn_exp2f(x);
#else
  return exp2f(x);
#endif
}

// ---------------------------------------------------------------------------
// Kernel 1: L2-normalize rows of h1,h2 (fp32), write bf16 H = [h1n; h2n]
// scaled by sqrt(2*log2 e) so the GEMM accumulator is already the exp2 arg.
// Also writes exact fp32 pos-dot per row (unscaled) and zeroes rowsum.
// One wave per row; block = 4 waves.
// ---------------------------------------------------------------------------
__global__ __launch_bounds__(256) void norm_kernel(
    const float* __restrict__ h1, const float* __restrict__ h2,
    __hip_bfloat16* __restrict__ Hb, float* __restrict__ posdot,
    float* __restrict__ rowsum) {
  // zero rowsum[16384]: 2048 blocks x 8 entries
  if (threadIdx.x < 8) rowsum[blockIdx.x * 8 + threadIdx.x] = 0.0f;

  int lane = threadIdx.x & 63;
  int w    = threadIdx.x >> 6;
  int row  = blockIdx.x * 4 + w;                  // 0..8191

  const float2* p1 = (const float2*)(h1 + (size_t)row * DIM);
  const float2* p2 = (const float2*)(h2 + (size_t)row * DIM);
  float2 v1 = p1[lane];
  float2 v2 = p2[lane];

  float ss1 = v1.x * v1.x + v1.y * v1.y;
  float ss2 = v2.x * v2.x + v2.y * v2.y;
  #pragma unroll
  for (int m = 32; m; m >>= 1) {
    ss1 += __shfl_xor(ss1, m);
    ss2 += __shfl_xor(ss2, m);
  }
  float inv1 = 1.0f / fmaxf(sqrtf(ss1), 1e-12f);
  float inv2 = 1.0f / fmaxf(sqrtf(ss2), 1e-12f);

  float ax = v1.x * inv1, ay = v1.y * inv1;
  float bx = v2.x * inv2, by = v2.y * inv2;

  float pd = ax * bx + ay * by;       // exact fp32 posdot (unscaled)
  #pragma unroll
  for (int m = 32; m; m >>= 1) pd += __shfl_xor(pd, m);

  __hip_bfloat162* o1 = (__hip_bfloat162*)(Hb + (size_t)row * DIM);
  __hip_bfloat162* o2 = (__hip_bfloat162*)(Hb + (size_t)(row + N_ROWS) * DIM);
  __hip_bfloat162 t1, t2;
  t1.x = __float2bfloat16(ax * H_SCALE); t1.y = __float2bfloat16(ay * H_SCALE);
  t2.x = __float2bfloat16(bx * H_SCALE); t2.y = __float2bfloat16(by * H_SCALE);
  o1[lane] = t1;
  o2[lane] = t2;

  if (lane == 0) posdot[row] = pd;
}

// ---------------------------------------------------------------------------
// Kernel 2: row sums of exp2(H H^T), upper block-triangle only (symmetry).
// H (4 MB) is L2-resident -> NO LDS staging of B, no per-tile barriers:
// each wave reads its B fragments straight from L2 into registers,
// double-buffered (b0/b1) so the next subtile's loads fly under MFMA+exp.
// Off-diagonal blocks reduce each exp tile along BOTH fragment axes:
//   rows  -> rowacc registers (stripe I)
//   cols  -> per-wave LDS slices, flushed once at the end (stripe J)
// Block: 256 threads = 4 waves; each wave owns 64 rows, A pinned in regs.
// The only __syncthreads is the final colacc exchange.
// ---------------------------------------------------------------------------
__global__ __launch_bounds__(256, 3) void ntx_main(
    const __hip_bfloat16* __restrict__ Hb, float* __restrict__ rowsum) {
  __shared__ float colacc[4][256];    // 4 KB: per-wave col-sum slices
  const short* H = (const short*)Hb;

  int tid  = threadIdx.x;
  int lane = tid & 63;
  int w    = tid >> 6;
  int q    = lane >> 4;     // k-chunk selector within fragment
  int m    = lane & 15;     // row-within-subtile / col-within-subtile

  // Triangular decode: blockIdx.x -> (I, J) with J >= I over NBLK stripes.
  int t = blockIdx.x;
  int I = (int)((129.0f - sqrtf(129.0f * 129.0f - 8.0f * (float)t)) * 0.5f);
  while ((I + 1) * (129 - (I + 1)) / 2 <= t) ++I;   // fixup fp rounding
  while (I * (129 - I) / 2 > t) --I;
  int J = I + (t - I * (129 - I) / 2);
  bool diag = (I == J);

  int rowbase = I * 256 + w * 64;
  int colbase = J * 256;

  // A fragments: 4 row-subtiles x 4 k-steps, held for the whole kernel.
  short8 a[4][4];
  #pragma unroll
  for (int r = 0; r < 4; ++r)
    #pragma unroll
    for (int s = 0; s < 4; ++s)
      a[r][s] = *(const short8*)(H + (size_t)(rowbase + r * 16 + m) * DIM + s * 32 + q * 8);
  // Pin A in registers: opaque volatile asm forbids remat/reload in the loop.
  #pragma unroll
  for (int r = 0; r < 4; ++r)
    #pragma unroll
    for (int s = 0; s < 4; ++s)
      asm volatile("" : "+v"(a[r][s]));

  float rowacc[4][4];
  #pragma unroll
  for (int r = 0; r < 4; ++r)
    #pragma unroll
    for (int i = 0; i < 4; ++i) rowacc[r][i] = 0.0f;

  // B fragment base for this lane: row (colbase + m), k-offset q*8 shorts.
  // Subtile cs covers cols colbase+cs*16 .. +15; advance 16 rows per subtile.
  const short* gp = H + (size_t)(colbase + m) * DIM + q * 8;

#define LOADB(bb, ptr) do {                         \
    bb[0] = *(const short8*)((ptr));                \
    bb[1] = *(const short8*)((ptr) + 32);           \
    bb[2] = *(const short8*)((ptr) + 64);           \
    bb[3] = *(const short8*)((ptr) + 96);           \
  } while (0)

#define COMPUTE(bb, cs_) do {                                              \
    float cp = 0.0f;                                                       \
    _Pragma("unroll")                                                      \
    for (int r = 0; r < 4; ++r) {                                          \
      float4v acc = {0.f, 0.f, 0.f, 0.f};                                  \
      _Pragma("unroll")                                                    \
      for (int s = 0; s < 4; ++s)                                          \
        acc = __builtin_amdgcn_mfma_f32_16x16x32_bf16(a[r][s], bb[s], acc, 0, 0, 0); \
      _Pragma("unroll")                                                    \
      for (int i = 0; i < 4; ++i) {                                        \
        float e = fast_exp2(acc[i]);   /* acc already = 2*log2e*dot */     \
        rowacc[r][i] += e;                                                 \
        cp += e;                                                           \
      }                                                                    \
    }                                                                      \
    if (!diag) {                                                           \
      cp += __shfl_xor(cp, 16);                                           \
      cp += __shfl_xor(cp, 32);                                           \
      if (q == 0) colacc[w][(cs_) * 16 + m] = cp;                          \
    }                                                                      \
  } while (0)

  short8 b0[4], b1[4];
  LOADB(b0, gp);
  #pragma unroll 1
  for (int cs = 0; cs < 16; cs += 2) {
    LOADB(b1, gp + 16 * DIM);          // subtile cs+1 in flight under COMPUTE
    COMPUTE(b0, cs);
    gp += 32 * DIM;
    if (cs + 2 < 16) LOADB(b0, gp);    // subtile cs+2 in flight
    COMPUTE(b1, cs + 1);
  }
#undef LOADB
#undef COMPUTE

  // Row sums: reduce across the 16 column-lanes holding the same rows.
  #pragma unroll
  for (int r = 0; r < 4; ++r)
    #pragma unroll
    for (int i = 0; i < 4; ++i) {
      float v = rowacc[r][i];
      v += __shfl_xor(v, 1);
      v += __shfl_xor(v, 2);
      v += __shfl_xor(v, 4);
      v += __shfl_xor(v, 8);
      rowacc[r][i] = v;
    }
  if (m == 0) {
    #pragma unroll
    for (int r = 0; r < 4; ++r)
      #pragma unroll
      for (int i = 0; i < 4; ++i)
        atomicAdd(&rowsum[rowbase + r * 16 + q * 4 + i], rowacc[r][i]);
  }

  // Col sums -> stripe J (symmetric contribution). One barrier total.
  if (!diag) {
    __syncthreads();
    float v = colacc[0][tid] + colacc[1][tid] + colacc[2][tid] + colacc[3][tid];
    atomicAdd(&rowsum[colbase + tid], v);
  }
}

// ---------------------------------------------------------------------------
// Kernel 3: loss = ( sum_i log(rowsum_i - e^2) - 4 * sum_i posdot_i ) / 2N
// float4 loads + 4 independent logf per iter to break the dependent chain.
// ---------------------------------------------------------------------------
__global__ __launch_bounds__(1024) void finalize(
    const float* __restrict__ rowsum, const float* __restrict__ posdot,
    float* __restrict__ out) {
  __shared__ float red[32];
  int tid = threadIdx.x;
  const float4* rs4 = (const float4*)rowsum;
  const float4* pd4 = (const float4*)posdot;
  float ld = 0.0f, pp = 0.0f;
  #pragma unroll
  for (int it = 0; it < 4; ++it) {
    float4 v = rs4[tid + it * 1024];
    ld += logf(v.x - EXP_TWO) + logf(v.y - EXP_TWO) +
          logf(v.z - EXP_TWO) + logf(v.w - EXP_TWO);
  }
  #pragma unroll
  for (int it = 0; it < 2; ++it) {
    float4 v = pd4[tid + it * 1024];
    pp += v.x + v.y + v.z + v.w;
  }
  #pragma unroll
  for (int m = 32; m; m >>= 1) {
    ld += __shfl_xor(ld, m);
    pp += __shfl_xor(pp, m);
  }
  if ((tid & 63) == 0) {
    red[tid >> 6] = ld;
    red[16 + (tid >> 6)] = pp;
  }
  __syncthreads();
  if (tid == 0) {
    float tl = 0.0f, tp = 0.0f;
    #pragma unroll
    for (int i = 0; i < 16; ++i) { tl += red[i]; tp += red[16 + i]; }
    *out = (tl - 4.0f * tp) / (float)TWO_N;
  }
}

extern "C" void kernel_launch(void* const* d_in, const int* in_sizes, int n_in,
                              void* d_out, int out_size, void* d_ws, size_t ws_size,
                              hipStream_t stream) {
  const float* h1 = (const float*)d_in[0];
  const float* h2 = (const float*)d_in[1];
  char* ws = (char*)d_ws;

  __hip_bfloat16* Hb = (__hip_bfloat16*)ws;                       // 4 MB
  float* rowsum      = (float*)(ws + 4194304);                    // 64 KB
  float* posdot      = (float*)(ws + 4194304 + 65536);            // 32 KB
  float* out         = (float*)d_out;

  norm_kernel<<<N_ROWS / 4, 256, 0, stream>>>(h1, h2, Hb, posdot, rowsum);
  ntx_main<<<NTRI, 256, 0, stream>>>(Hb, rowsum);
  finalize<<<1, 1024, 0, stream>>>(rowsum, posdot, out);
}